// Round 10
// baseline (92.844 us; speedup 1.0000x reference)
//
#include <hip/hip_runtime.h>

#define N_NODES 40000
#define D 128
#define N_EDGES 640000
#define CAP 64      // max in-degree per node (proven sufficient rounds 4/8/9)
#define GRP 128     // dst nodes per key group
#define NKEY 313    // ceil(N_NODES / GRP)
#define P1TILE 2048 // edges per partition tile
#define P1BLKS 313  // ceil(N_EDGES / P1TILE); last tile has 1024 edges
// src-degree histogram (proven rounds 7-9):
#define NSLICE 32
#define SLICE_E 20000
#define SLICE_E4 5000
#define HALF_BINS 20000
#define HALF_W 10000
#define WROW 20000
#define SRCH_BLKS 64
#define GEMM_BLKS 625  // x 64 nodes
#define XPAD 132

typedef __attribute__((ext_vector_type(8))) short short8_t;
typedef __attribute__((ext_vector_type(4))) float float4_t;

static __device__ __forceinline__ unsigned short f2bf(float f) {
  unsigned u = __float_as_uint(f);
  return (unsigned short)((u + 0x7fffu + ((u >> 16) & 1u)) >> 16);  // RNE
}
static __device__ __forceinline__ float bf2f(unsigned short h) {
  return __uint_as_float(((unsigned)h) << 16);
}

// Inclusive Hillis-Steele scan over s[0..511]; 256 threads, 2 indices each.
// Caller must __syncthreads() before calling; ends synced.
static __device__ __forceinline__ void scan512(unsigned* s, int tid) {
  const int t2 = tid + 256;
#pragma unroll
  for (int off = 1; off < 512; off <<= 1) {
    unsigned a = (tid >= off) ? s[tid - off] : 0u;
    unsigned c = (t2 >= off) ? s[t2 - off] : 0u;
    __syncthreads();
    s[tid] += a;
    s[t2] += c;
    __syncthreads();
  }
}

// ---------------------------------------------------------------------------
// k_prep: repack W (fp32 [128][128]) into bf16 MFMA B-fragments (round-9).
// ---------------------------------------------------------------------------
__global__ __launch_bounds__(256) void k_prep(const float* __restrict__ W,
                                              unsigned short* __restrict__ Wb) {
  const int g = blockIdx.x * 256 + threadIdx.x;  // 0..16383
  const int j = g & 7;
  const int lane = (g >> 3) & 63;
  const int q = (g >> 9) & 3;
  const int t = g >> 11;
  const int k = q * 32 + (lane >> 4) * 8 + j;
  const int d = t * 16 + (lane & 15);
  Wb[g] = f2bf(W[k * D + d]);
}

// ---------------------------------------------------------------------------
// k1 — three roles, no global atomics:
//  bid < 64           : src-hist slab (proven): u16-packed LDS histogram.
//  t=bid-64, t%3==2   : p1-hist: LDS count of dst>>7 keys for tile t/3,
//                       slab row out (coalesced 313 ints).
//  else               : MFMA GEMM (round-9 proven): hb = bf16(x@W) unscaled.
// ---------------------------------------------------------------------------
__global__ __launch_bounds__(256) void k1(
    const float* __restrict__ x, const unsigned short* __restrict__ Wb,
    const int* __restrict__ src, const int* __restrict__ dst,
    unsigned* __restrict__ slabS, unsigned* __restrict__ slabP,
    unsigned short* __restrict__ hb) {
  __shared__ unsigned smem[10240];  // 40KB union
  const int bid = blockIdx.x;
  const int tid = threadIdx.x;

  if (bid < SRCH_BLKS) {
    // ---------------- src histogram role ----------------
    const int b = bid >> 1;
    const int h = bid & 1;
    for (int i = tid; i < HALF_W; i += 256) smem[i] = 0;
    __syncthreads();
    const int4* p4 = (const int4*)(src + b * SLICE_E);
    const unsigned lo = (unsigned)(h * HALF_BINS);
    for (int it = tid; it < SLICE_E4; it += 256) {
      const int4 v = p4[it];
      unsigned u;
      u = (unsigned)v.x - lo; if (u < HALF_BINS) atomicAdd(&smem[u >> 1], 1u << ((u & 1) * 16));
      u = (unsigned)v.y - lo; if (u < HALF_BINS) atomicAdd(&smem[u >> 1], 1u << ((u & 1) * 16));
      u = (unsigned)v.z - lo; if (u < HALF_BINS) atomicAdd(&smem[u >> 1], 1u << ((u & 1) * 16));
      u = (unsigned)v.w - lo; if (u < HALF_BINS) atomicAdd(&smem[u >> 1], 1u << ((u & 1) * 16));
    }
    __syncthreads();
    unsigned* row = slabS + (size_t)b * WROW + h * HALF_W;
    for (int i = tid; i < HALF_W; i += 256) row[i] = smem[i];
    return;
  }

  const int t = bid - SRCH_BLKS;
  if (t % 3 == 2) {
    // ---------------- p1-hist role ----------------
    const int cid = t / 3;  // 0..312
    unsigned* cnt = smem;   // [NKEY]
    const int t2 = tid + 256;
    if (tid < NKEY) cnt[tid] = 0;
    if (t2 < NKEY) cnt[t2] = 0;
    __syncthreads();
    const int e0 = cid * P1TILE + tid * 8;
    if (e0 < N_EDGES) {
      const int4 da = *(const int4*)(dst + e0);
      const int4 db = *(const int4*)(dst + e0 + 4);
      atomicAdd(&cnt[da.x >> 7], 1u);
      atomicAdd(&cnt[da.y >> 7], 1u);
      atomicAdd(&cnt[da.z >> 7], 1u);
      atomicAdd(&cnt[da.w >> 7], 1u);
      atomicAdd(&cnt[db.x >> 7], 1u);
      atomicAdd(&cnt[db.y >> 7], 1u);
      atomicAdd(&cnt[db.z >> 7], 1u);
      atomicAdd(&cnt[db.w >> 7], 1u);
    }
    __syncthreads();
    if (tid < NKEY) slabP[(size_t)cid * NKEY + tid] = cnt[tid];
    if (t2 < NKEY) slabP[(size_t)cid * NKEY + t2] = cnt[t2];
    return;
  }

  // ---------------- MFMA GEMM role (round-9 proven) ----------------
  const int gid = 2 * (t / 3) + (t % 3);
  if (gid >= GEMM_BLKS) return;
  const int n0 = gid * 64;
  const int w = tid >> 6;
  const int lane = tid & 63;

  float* xl = (float*)smem;  // [64][XPAD]
  {
    const float4* xg = (const float4*)(x + (size_t)n0 * D);
#pragma unroll
    for (int j = 0; j < 8; ++j) {
      const int idx = tid + j * 256;
      const int row = idx >> 5;
      const int c4 = idx & 31;
      ((float4*)(xl + row * XPAD))[c4] = xg[idx];
    }
  }
  __syncthreads();

  short8_t afrag[4];
  {
    const float* ap0 = xl + (w * 16 + (lane & 15)) * XPAD + (lane >> 4) * 8;
#pragma unroll
    for (int q = 0; q < 4; ++q) {
      const float* ap = ap0 + q * 32;
      const float4 v0 = *(const float4*)ap;
      const float4 v1 = *(const float4*)(ap + 4);
      short8_t a;
      a[0] = (short)f2bf(v0.x); a[1] = (short)f2bf(v0.y);
      a[2] = (short)f2bf(v0.z); a[3] = (short)f2bf(v0.w);
      a[4] = (short)f2bf(v1.x); a[5] = (short)f2bf(v1.y);
      a[6] = (short)f2bf(v1.z); a[7] = (short)f2bf(v1.w);
      afrag[q] = a;
    }
  }

  const int orow = n0 + w * 16 + (lane >> 4) * 4;
  const int ocolbase = lane & 15;
#pragma unroll
  for (int t8 = 0; t8 < 8; ++t8) {
    float4_t acc = {0.f, 0.f, 0.f, 0.f};
#pragma unroll
    for (int q = 0; q < 4; ++q) {
      const short8_t bfrag =
          *(const short8_t*)(Wb + ((size_t)(t8 * 4 + q) * 64 + lane) * 8);
      acc = __builtin_amdgcn_mfma_f32_16x16x32_bf16(afrag[q], bfrag, acc, 0, 0, 0);
    }
    const int col = t8 * 16 + ocolbase;
#pragma unroll
    for (int r = 0; r < 4; ++r)
      hb[(size_t)(orow + r) * D + col] = f2bf(acc[r]);
  }
}

// ---------------------------------------------------------------------------
// k2 — bid < NKEY: per-key exclusive prefix over tiles -> rowbase, total ->
//       keytotal.  bid >= NKEY: dinv colsum from src slab (proven).
// ---------------------------------------------------------------------------
__global__ __launch_bounds__(256) void k2(
    const unsigned* __restrict__ slabP, const unsigned* __restrict__ slabS,
    unsigned* __restrict__ rowbase, unsigned* __restrict__ keytotal,
    float* __restrict__ dinv) {
  const int bid = blockIdx.x;
  const int tid = threadIdx.x;
  if (bid < NKEY) {
    const int k = bid;
    __shared__ unsigned s[512];
    const int t2 = tid + 256;
    unsigned v0 = slabP[(size_t)tid * NKEY + k];  // tid < 256 < NKEY always
    unsigned v1 = (t2 < NKEY) ? slabP[(size_t)t2 * NKEY + k] : 0u;
    s[tid] = v0;
    s[t2] = v1;
    __syncthreads();
    scan512(s, tid);
    rowbase[(size_t)tid * NKEY + k] = s[tid] - v0;
    if (t2 < NKEY) rowbase[(size_t)t2 * NKEY + k] = s[t2] - v1;
    if (tid == 0) keytotal[k] = s[NKEY - 1];
    return;
  }
  const int w = (bid - NKEY) * 256 + tid;
  if (w >= WROW) return;
  unsigned run = 0;
#pragma unroll 8
  for (int b = 0; b < NSLICE; ++b) run += slabS[(size_t)b * WROW + w];
  const unsigned lo = run & 0xFFFFu;
  const unsigned hi = run >> 16;
  dinv[2 * w] = lo ? 1.0f / (float)lo : 0.0f;
  dinv[2 * w + 1] = hi ? 1.0f / (float)hi : 0.0f;
}

// ---------------------------------------------------------------------------
// k3 — partition scatter: edge -> epack[keyoff[key] + rowbase[tile][key] +
//      LDS-rank], pack = (dst&127)<<16 | src.  Each (tile,key) run is
//      block-exclusive -> line sharing only at run boundaries.
// ---------------------------------------------------------------------------
__global__ __launch_bounds__(256) void k3(
    const int* __restrict__ src, const int* __restrict__ dst,
    const unsigned* __restrict__ rowbase, const unsigned* __restrict__ keytotal,
    unsigned* __restrict__ epack) {
  __shared__ unsigned s[512];
  __shared__ unsigned ko[NKEY];
  __shared__ unsigned rb[NKEY];
  __shared__ unsigned cnt[NKEY];
  const int b = blockIdx.x;
  const int tid = threadIdx.x;
  const int t2 = tid + 256;

  unsigned kv0 = (tid < NKEY) ? keytotal[tid] : 0u;
  unsigned kv1 = (t2 < NKEY) ? keytotal[t2] : 0u;
  s[tid] = kv0;
  s[t2] = kv1;
  if (tid < NKEY) { rb[tid] = rowbase[(size_t)b * NKEY + tid]; cnt[tid] = 0; }
  if (t2 < NKEY) { rb[t2] = rowbase[(size_t)b * NKEY + t2]; cnt[t2] = 0; }
  __syncthreads();
  scan512(s, tid);
  if (tid < NKEY) ko[tid] = s[tid] - kv0;  // exclusive key offset
  if (t2 < NKEY) ko[t2] = s[t2] - kv1;
  __syncthreads();

  const int e0 = b * P1TILE + tid * 8;
  if (e0 < N_EDGES) {
    const int4 sa = *(const int4*)(src + e0);
    const int4 sb = *(const int4*)(src + e0 + 4);
    const int4 da = *(const int4*)(dst + e0);
    const int4 db = *(const int4*)(dst + e0 + 4);
#define PLACE(DV, SV)                                                   \
  {                                                                     \
    const int d_ = (DV);                                                \
    const int k_ = d_ >> 7;                                             \
    const unsigned lr_ = atomicAdd(&cnt[k_], 1u);                       \
    epack[ko[k_] + rb[k_] + lr_] =                                      \
        ((unsigned)(d_ & 127) << 16) | (unsigned)(SV);                  \
  }
    PLACE(da.x, sa.x) PLACE(da.y, sa.y) PLACE(da.z, sa.z) PLACE(da.w, sa.w)
    PLACE(db.x, sb.x) PLACE(db.y, sb.y) PLACE(db.z, sb.z) PLACE(db.w, sb.w)
#undef PLACE
  }
}

// ---------------------------------------------------------------------------
// k4 — per key group (128 dst nodes): build CSR bucket in LDS (LDS-atomic
//      ranks), then proven 4-chain gather: out[n] = b + sum dinv[s]*hb[s].
// ---------------------------------------------------------------------------
__global__ __launch_bounds__(256) void k4(
    const unsigned* __restrict__ keytotal, const unsigned* __restrict__ epack,
    const float* __restrict__ dinv, const unsigned short* __restrict__ hb,
    const float* __restrict__ bvec, float* __restrict__ out) {
  __shared__ unsigned s[512];
  __shared__ unsigned cnt[GRP];
  __shared__ unsigned short bkt[GRP * CAP];  // 16KB
  const int k = blockIdx.x;
  const int tid = threadIdx.x;
  const int t2 = tid + 256;

  unsigned kv0 = (tid < NKEY) ? keytotal[tid] : 0u;
  unsigned kv1 = (t2 < NKEY) ? keytotal[t2] : 0u;
  s[tid] = kv0;
  s[t2] = kv1;
  if (tid < GRP) cnt[tid] = 0;
  __syncthreads();
  scan512(s, tid);
  const unsigned start = (k > 0) ? s[k - 1] : 0u;
  const unsigned len = s[k] - start;
  __syncthreads();

  for (unsigned i = tid; i < len; i += 256) {
    const unsigned p = epack[start + i];
    const unsigned dl = p >> 16;
    const unsigned sr = p & 0xFFFFu;
    const unsigned r = atomicAdd(&cnt[dl], 1u);
    if (r < CAP) bkt[dl * CAP + r] = (unsigned short)sr;
  }
  __syncthreads();

  const int lane = tid & 31;
  const int g = tid >> 5;  // 0..7
  const float4 bias = ((const float4*)bvec)[lane];
#pragma unroll 1
  for (int c = 0; c < 16; ++c) {
    const int nl = c * 8 + g;
    const int n = k * GRP + nl;
    if (n >= N_NODES) continue;
    int ln = (int)cnt[nl];
    if (ln > CAP) ln = CAP;
    const unsigned short* bk = bkt + nl * CAP;

    float4 a0 = {0.f, 0.f, 0.f, 0.f};
    float4 a1 = {0.f, 0.f, 0.f, 0.f};
    float4 a2 = {0.f, 0.f, 0.f, 0.f};
    float4 a3 = {0.f, 0.f, 0.f, 0.f};
    int j = 0;
    for (; j + 3 < ln; j += 4) {
      const int s0 = bk[j + 0];
      const int s1 = bk[j + 1];
      const int s2 = bk[j + 2];
      const int s3 = bk[j + 3];
      const float f0 = dinv[s0];
      const float f1 = dinv[s1];
      const float f2 = dinv[s2];
      const float f3 = dinv[s3];
      ushort4 u0 = ((const ushort4*)(hb + (size_t)s0 * D))[lane];
      ushort4 u1 = ((const ushort4*)(hb + (size_t)s1 * D))[lane];
      ushort4 u2 = ((const ushort4*)(hb + (size_t)s2 * D))[lane];
      ushort4 u3 = ((const ushort4*)(hb + (size_t)s3 * D))[lane];
      a0.x += f0 * bf2f(u0.x); a0.y += f0 * bf2f(u0.y); a0.z += f0 * bf2f(u0.z); a0.w += f0 * bf2f(u0.w);
      a1.x += f1 * bf2f(u1.x); a1.y += f1 * bf2f(u1.y); a1.z += f1 * bf2f(u1.z); a1.w += f1 * bf2f(u1.w);
      a2.x += f2 * bf2f(u2.x); a2.y += f2 * bf2f(u2.y); a2.z += f2 * bf2f(u2.z); a2.w += f2 * bf2f(u2.w);
      a3.x += f3 * bf2f(u3.x); a3.y += f3 * bf2f(u3.y); a3.z += f3 * bf2f(u3.z); a3.w += f3 * bf2f(u3.w);
    }
    for (; j < ln; ++j) {
      const int s0 = bk[j];
      const float f0 = dinv[s0];
      ushort4 u0 = ((const ushort4*)(hb + (size_t)s0 * D))[lane];
      a0.x += f0 * bf2f(u0.x); a0.y += f0 * bf2f(u0.y); a0.z += f0 * bf2f(u0.z); a0.w += f0 * bf2f(u0.w);
    }
    float4 v;
    v.x = bias.x + (a0.x + a1.x) + (a2.x + a3.x);
    v.y = bias.y + (a0.y + a1.y) + (a2.y + a3.y);
    v.z = bias.z + (a0.z + a1.z) + (a2.z + a3.z);
    v.w = bias.w + (a0.w + a1.w) + (a2.w + a3.w);
    ((float4*)(out + (size_t)n * D))[lane] = v;
  }
}

extern "C" void kernel_launch(void* const* d_in, const int* in_sizes, int n_in,
                              void* d_out, int out_size, void* d_ws, size_t ws_size,
                              hipStream_t stream) {
  const float* x = (const float*)d_in[0];
  const float* W = (const float*)d_in[1];
  const float* b = (const float*)d_in[2];
  const int* ei = (const int*)d_in[3];
  const int* src = ei;            // edge_index[0]
  const int* dst = ei + N_EDGES;  // edge_index[1]
  float* out = (float*)d_out;

  char* ws = (char*)d_ws;
  float* dinv = (float*)(ws + 0);                        // 160,000
  unsigned* slabS = (unsigned*)(ws + 160000);            // 2,560,000
  unsigned short* Wb = (unsigned short*)(ws + 2720000);  // 32,768
  unsigned* slabP = (unsigned*)(ws + 2752768);           // 391,876 (+pad)
  unsigned* rowbase = (unsigned*)(ws + 3144704);         // 391,876 (+pad)
  unsigned* keytotal = (unsigned*)(ws + 3536640);        // 1,252 (+pad)
  unsigned* epack = (unsigned*)(ws + 3540992);           // 2,560,000
  unsigned short* hb = (unsigned short*)(ws + 6100992);  // 10,240,000 (16.3 MB)

  k_prep<<<64, 256, 0, stream>>>(W, Wb);
  k1<<<SRCH_BLKS + 939, 256, 0, stream>>>(x, Wb, src, dst, slabS, slabP, hb);
  k2<<<NKEY + 79, 256, 0, stream>>>(slabP, slabS, rowbase, keytotal, dinv);
  k3<<<P1BLKS, 256, 0, stream>>>(src, dst, rowbase, keytotal, epack);
  k4<<<NKEY, 256, 0, stream>>>(keytotal, epack, dinv, hb, b, out);
}

// Round 11
// 73.388 us; speedup vs baseline: 1.2651x; 1.2651x over previous
//
#include <hip/hip_runtime.h>

#define N_NODES 40000
#define D 128
#define N_EDGES 640000
#define GRP 128     // dst nodes per key group
#define NKEY 313    // ceil(N_NODES / GRP)
#define P1TILE 2048 // edges per partition tile
#define P1BLKS 313  // ceil(N_EDGES / P1TILE)
// src-degree histogram (proven rounds 7-10):
#define NSLICE 32
#define SLICE_E 20000
#define SLICE_E4 5000
#define HALF_BINS 20000
#define HALF_W 10000
#define WROW 20000
#define SRCH_BLKS 64
#define GEMM_BLKS 625  // x 64 nodes
#define XPAD 132

typedef __attribute__((ext_vector_type(8))) short short8_t;
typedef __attribute__((ext_vector_type(4))) float float4_t;

static __device__ __forceinline__ unsigned short f2bf(float f) {
  unsigned u = __float_as_uint(f);
  return (unsigned short)((u + 0x7fffu + ((u >> 16) & 1u)) >> 16);  // RNE
}
static __device__ __forceinline__ float bf2f(unsigned short h) {
  return __uint_as_float(((unsigned)h) << 16);
}

// Inclusive Hillis-Steele scan over s[0..511]; 256 threads, 2 indices each.
static __device__ __forceinline__ void scan512(unsigned* s, int tid) {
  const int t2 = tid + 256;
#pragma unroll
  for (int off = 1; off < 512; off <<= 1) {
    unsigned a = (tid >= off) ? s[tid - off] : 0u;
    unsigned c = (t2 >= off) ? s[t2 - off] : 0u;
    __syncthreads();
    s[tid] += a;
    s[t2] += c;
    __syncthreads();
  }
}

// ---------------------------------------------------------------------------
// k_prep: repack W (fp32 [128][128]) into bf16 MFMA B-fragments (round-9).
// ---------------------------------------------------------------------------
__global__ __launch_bounds__(256) void k_prep(const float* __restrict__ W,
                                              unsigned short* __restrict__ Wb) {
  const int g = blockIdx.x * 256 + threadIdx.x;  // 0..16383
  const int j = g & 7;
  const int lane = (g >> 3) & 63;
  const int q = (g >> 9) & 3;
  const int t = g >> 11;
  const int k = q * 32 + (lane >> 4) * 8 + j;
  const int d = t * 16 + (lane & 15);
  Wb[g] = f2bf(W[k * D + d]);
}

// ---------------------------------------------------------------------------
// k1 — three roles (round-10 proven), no global atomics:
//  bid < 64         : src-hist slab, u16-packed LDS histogram.
//  t=bid-64, t%3==2 : p1-hist: LDS count of dst>>7 keys for tile t/3.
//  else             : MFMA GEMM: hb = bf16(x@W) unscaled.
// ---------------------------------------------------------------------------
__global__ __launch_bounds__(256) void k1(
    const float* __restrict__ x, const unsigned short* __restrict__ Wb,
    const int* __restrict__ src, const int* __restrict__ dst,
    unsigned* __restrict__ slabS, unsigned* __restrict__ slabP,
    unsigned short* __restrict__ hb) {
  __shared__ unsigned smem[10240];  // 40KB union
  const int bid = blockIdx.x;
  const int tid = threadIdx.x;

  if (bid < SRCH_BLKS) {
    const int b = bid >> 1;
    const int h = bid & 1;
    for (int i = tid; i < HALF_W; i += 256) smem[i] = 0;
    __syncthreads();
    const int4* p4 = (const int4*)(src + b * SLICE_E);
    const unsigned lo = (unsigned)(h * HALF_BINS);
    for (int it = tid; it < SLICE_E4; it += 256) {
      const int4 v = p4[it];
      unsigned u;
      u = (unsigned)v.x - lo; if (u < HALF_BINS) atomicAdd(&smem[u >> 1], 1u << ((u & 1) * 16));
      u = (unsigned)v.y - lo; if (u < HALF_BINS) atomicAdd(&smem[u >> 1], 1u << ((u & 1) * 16));
      u = (unsigned)v.z - lo; if (u < HALF_BINS) atomicAdd(&smem[u >> 1], 1u << ((u & 1) * 16));
      u = (unsigned)v.w - lo; if (u < HALF_BINS) atomicAdd(&smem[u >> 1], 1u << ((u & 1) * 16));
    }
    __syncthreads();
    unsigned* row = slabS + (size_t)b * WROW + h * HALF_W;
    for (int i = tid; i < HALF_W; i += 256) row[i] = smem[i];
    return;
  }

  const int t = bid - SRCH_BLKS;
  if (t % 3 == 2) {
    const int cid = t / 3;  // 0..312
    unsigned* cnt = smem;   // [NKEY]
    const int t2 = tid + 256;
    if (tid < NKEY) cnt[tid] = 0;
    if (t2 < NKEY) cnt[t2] = 0;
    __syncthreads();
    const int e0 = cid * P1TILE + tid * 8;
    if (e0 < N_EDGES) {
      const int4 da = *(const int4*)(dst + e0);
      const int4 db = *(const int4*)(dst + e0 + 4);
      atomicAdd(&cnt[da.x >> 7], 1u);
      atomicAdd(&cnt[da.y >> 7], 1u);
      atomicAdd(&cnt[da.z >> 7], 1u);
      atomicAdd(&cnt[da.w >> 7], 1u);
      atomicAdd(&cnt[db.x >> 7], 1u);
      atomicAdd(&cnt[db.y >> 7], 1u);
      atomicAdd(&cnt[db.z >> 7], 1u);
      atomicAdd(&cnt[db.w >> 7], 1u);
    }
    __syncthreads();
    if (tid < NKEY) slabP[(size_t)cid * NKEY + tid] = cnt[tid];
    if (t2 < NKEY) slabP[(size_t)cid * NKEY + t2] = cnt[t2];
    return;
  }

  // ---------------- MFMA GEMM role ----------------
  const int gid = 2 * (t / 3) + (t % 3);
  if (gid >= GEMM_BLKS) return;
  const int n0 = gid * 64;
  const int w = tid >> 6;
  const int lane = tid & 63;

  float* xl = (float*)smem;  // [64][XPAD]
  {
    const float4* xg = (const float4*)(x + (size_t)n0 * D);
#pragma unroll
    for (int j = 0; j < 8; ++j) {
      const int idx = tid + j * 256;
      const int row = idx >> 5;
      const int c4 = idx & 31;
      ((float4*)(xl + row * XPAD))[c4] = xg[idx];
    }
  }
  __syncthreads();

  short8_t afrag[4];
  {
    const float* ap0 = xl + (w * 16 + (lane & 15)) * XPAD + (lane >> 4) * 8;
#pragma unroll
    for (int q = 0; q < 4; ++q) {
      const float* ap = ap0 + q * 32;
      const float4 v0 = *(const float4*)ap;
      const float4 v1 = *(const float4*)(ap + 4);
      short8_t a;
      a[0] = (short)f2bf(v0.x); a[1] = (short)f2bf(v0.y);
      a[2] = (short)f2bf(v0.z); a[3] = (short)f2bf(v0.w);
      a[4] = (short)f2bf(v1.x); a[5] = (short)f2bf(v1.y);
      a[6] = (short)f2bf(v1.z); a[7] = (short)f2bf(v1.w);
      afrag[q] = a;
    }
  }

  const int orow = n0 + w * 16 + (lane >> 4) * 4;
  const int ocolbase = lane & 15;
#pragma unroll
  for (int t8 = 0; t8 < 8; ++t8) {
    float4_t acc = {0.f, 0.f, 0.f, 0.f};
#pragma unroll
    for (int q = 0; q < 4; ++q) {
      const short8_t bfrag =
          *(const short8_t*)(Wb + ((size_t)(t8 * 4 + q) * 64 + lane) * 8);
      acc = __builtin_amdgcn_mfma_f32_16x16x32_bf16(afrag[q], bfrag, acc, 0, 0, 0);
    }
    const int col = t8 * 16 + ocolbase;
#pragma unroll
    for (int r = 0; r < 4; ++r)
      hb[(size_t)(orow + r) * D + col] = f2bf(acc[r]);
  }
}

// ---------------------------------------------------------------------------
// k2 — bid < NKEY: per-key exclusive prefix over tiles -> rowbase + keytotal.
//      bid >= NKEY: dinv colsum from src slab. (round-10 proven)
// ---------------------------------------------------------------------------
__global__ __launch_bounds__(256) void k2(
    const unsigned* __restrict__ slabP, const unsigned* __restrict__ slabS,
    unsigned* __restrict__ rowbase, unsigned* __restrict__ keytotal,
    float* __restrict__ dinv) {
  const int bid = blockIdx.x;
  const int tid = threadIdx.x;
  if (bid < NKEY) {
    const int k = bid;
    __shared__ unsigned s[512];
    const int t2 = tid + 256;
    unsigned v0 = slabP[(size_t)tid * NKEY + k];
    unsigned v1 = (t2 < NKEY) ? slabP[(size_t)t2 * NKEY + k] : 0u;
    s[tid] = v0;
    s[t2] = v1;
    __syncthreads();
    scan512(s, tid);
    rowbase[(size_t)tid * NKEY + k] = s[tid] - v0;
    if (t2 < NKEY) rowbase[(size_t)t2 * NKEY + k] = s[t2] - v1;
    if (tid == 0) keytotal[k] = s[NKEY - 1];
    return;
  }
  const int w = (bid - NKEY) * 256 + tid;
  if (w >= WROW) return;
  unsigned run = 0;
#pragma unroll 8
  for (int b = 0; b < NSLICE; ++b) run += slabS[(size_t)b * WROW + w];
  const unsigned lo = run & 0xFFFFu;
  const unsigned hi = run >> 16;
  dinv[2 * w] = lo ? 1.0f / (float)lo : 0.0f;
  dinv[2 * w + 1] = hi ? 1.0f / (float)hi : 0.0f;
}

// ---------------------------------------------------------------------------
// k3 — partition scatter (round-10 proven): edge -> epack[ko[key] +
//      rowbase[tile][key] + LDS-rank], pack = (dst&127)<<16 | src.
// ---------------------------------------------------------------------------
__global__ __launch_bounds__(256) void k3(
    const int* __restrict__ src, const int* __restrict__ dst,
    const unsigned* __restrict__ rowbase, const unsigned* __restrict__ keytotal,
    unsigned* __restrict__ epack) {
  __shared__ unsigned s[512];
  __shared__ unsigned ko[NKEY];
  __shared__ unsigned rb[NKEY];
  __shared__ unsigned cnt[NKEY];
  const int b = blockIdx.x;
  const int tid = threadIdx.x;
  const int t2 = tid + 256;

  unsigned kv0 = (tid < NKEY) ? keytotal[tid] : 0u;
  unsigned kv1 = (t2 < NKEY) ? keytotal[t2] : 0u;
  s[tid] = kv0;
  s[t2] = kv1;
  if (tid < NKEY) { rb[tid] = rowbase[(size_t)b * NKEY + tid]; cnt[tid] = 0; }
  if (t2 < NKEY) { rb[t2] = rowbase[(size_t)b * NKEY + t2]; cnt[t2] = 0; }
  __syncthreads();
  scan512(s, tid);
  if (tid < NKEY) ko[tid] = s[tid] - kv0;
  if (t2 < NKEY) ko[t2] = s[t2] - kv1;
  __syncthreads();

  const int e0 = b * P1TILE + tid * 8;
  if (e0 < N_EDGES) {
    const int4 sa = *(const int4*)(src + e0);
    const int4 sb = *(const int4*)(src + e0 + 4);
    const int4 da = *(const int4*)(dst + e0);
    const int4 db = *(const int4*)(dst + e0 + 4);
#define PLACE(DV, SV)                                                   \
  {                                                                     \
    const int d_ = (DV);                                                \
    const int k_ = d_ >> 7;                                             \
    const unsigned lr_ = atomicAdd(&cnt[k_], 1u);                       \
    epack[ko[k_] + rb[k_] + lr_] =                                      \
        ((unsigned)(d_ & 127) << 16) | (unsigned)(SV);                  \
  }
    PLACE(da.x, sa.x) PLACE(da.y, sa.y) PLACE(da.z, sa.z) PLACE(da.w, sa.w)
    PLACE(db.x, sb.x) PLACE(db.y, sb.y) PLACE(db.z, sb.z) PLACE(db.w, sb.w)
#undef PLACE
  }
}

// ---------------------------------------------------------------------------
// k4a — per key group: dense CSR materialization. Two passes over the
//       group's epack run: LDS hist(128) -> scan -> exact offs/cnt_dst,
//       esrc16 written into the block-private contiguous region.
// ---------------------------------------------------------------------------
__global__ __launch_bounds__(256) void k4a(
    const unsigned* __restrict__ keytotal, const unsigned* __restrict__ epack,
    int* __restrict__ offs, int* __restrict__ cnt_dst,
    unsigned short* __restrict__ esrc16) {
  __shared__ unsigned s[512];
  __shared__ unsigned cnt[GRP];
  __shared__ unsigned loc[GRP];
  __shared__ unsigned cur[GRP];
  __shared__ unsigned sstart, slen;
  const int k = blockIdx.x;
  const int tid = threadIdx.x;
  const int t2 = tid + 256;

  unsigned kv0 = (tid < NKEY) ? keytotal[tid] : 0u;
  unsigned kv1 = (t2 < NKEY) ? keytotal[t2] : 0u;
  s[tid] = kv0;
  s[t2] = kv1;
  if (tid < GRP) cnt[tid] = 0;
  __syncthreads();
  scan512(s, tid);
  if (tid == 0) {
    sstart = s[k] - keytotal[k];  // exclusive key offset
    slen = keytotal[k];
  }
  __syncthreads();
  const unsigned start = sstart;
  const unsigned len = slen;

  // pass 1: per-node counts
  for (unsigned i = tid; i < len; i += 256) {
    atomicAdd(&cnt[epack[start + i] >> 16], 1u);
  }
  __syncthreads();

  // exclusive scan of 128 counts (256-wide Hillis-Steele, upper half zero)
  unsigned v = (tid < GRP) ? cnt[tid] : 0u;
  s[tid] = v;
  __syncthreads();
#pragma unroll
  for (int off = 1; off < 256; off <<= 1) {
    unsigned a = (tid >= off) ? s[tid - off] : 0u;
    __syncthreads();
    s[tid] += a;
    __syncthreads();
  }
  if (tid < GRP) {
    const unsigned ex = s[tid] - v;
    loc[tid] = ex;
    cur[tid] = ex;
    const int n = k * GRP + tid;
    if (n < N_NODES) {
      offs[n] = (int)(start + ex);
      cnt_dst[n] = (int)v;
    }
  }
  __syncthreads();

  // pass 2: place (block-private contiguous region of esrc16)
  for (unsigned i = tid; i < len; i += 256) {
    const unsigned p = epack[start + i];
    const unsigned dl = p >> 16;
    const unsigned r = atomicAdd(&cur[dl], 1u);
    esrc16[start + r] = (unsigned short)(p & 0xFFFFu);
  }
}

// ---------------------------------------------------------------------------
// k4b — round-8 proven gather (5000 blocks): out[n] = b + sum dinv[s]*hb[s]
//       over the dense CSR. 32 lanes/node, 8 nodes/block, 4 acc chains.
// ---------------------------------------------------------------------------
__global__ __launch_bounds__(256) void k4b(
    const int* __restrict__ offs, const int* __restrict__ cnt_dst,
    const float* __restrict__ dinv, const unsigned short* __restrict__ esrc16,
    const unsigned short* __restrict__ hb,
    const float* __restrict__ b, float* __restrict__ out) {
  const int tid = threadIdx.x;
  const int node = blockIdx.x * 8 + (tid >> 5);
  const int lane = tid & 31;

  const int start = offs[node];
  const int len = cnt_dst[node];
  const unsigned short* bk = esrc16 + start;

  float4 a0 = {0.f, 0.f, 0.f, 0.f};
  float4 a1 = {0.f, 0.f, 0.f, 0.f};
  float4 a2 = {0.f, 0.f, 0.f, 0.f};
  float4 a3 = {0.f, 0.f, 0.f, 0.f};

  int j = 0;
  for (; j + 3 < len; j += 4) {
    const int s0 = bk[j + 0];
    const int s1 = bk[j + 1];
    const int s2 = bk[j + 2];
    const int s3 = bk[j + 3];
    const float f0 = dinv[s0];
    const float f1 = dinv[s1];
    const float f2 = dinv[s2];
    const float f3 = dinv[s3];
    ushort4 u0 = ((const ushort4*)(hb + (size_t)s0 * D))[lane];
    ushort4 u1 = ((const ushort4*)(hb + (size_t)s1 * D))[lane];
    ushort4 u2 = ((const ushort4*)(hb + (size_t)s2 * D))[lane];
    ushort4 u3 = ((const ushort4*)(hb + (size_t)s3 * D))[lane];
    a0.x += f0 * bf2f(u0.x); a0.y += f0 * bf2f(u0.y); a0.z += f0 * bf2f(u0.z); a0.w += f0 * bf2f(u0.w);
    a1.x += f1 * bf2f(u1.x); a1.y += f1 * bf2f(u1.y); a1.z += f1 * bf2f(u1.z); a1.w += f1 * bf2f(u1.w);
    a2.x += f2 * bf2f(u2.x); a2.y += f2 * bf2f(u2.y); a2.z += f2 * bf2f(u2.z); a2.w += f2 * bf2f(u2.w);
    a3.x += f3 * bf2f(u3.x); a3.y += f3 * bf2f(u3.y); a3.z += f3 * bf2f(u3.z); a3.w += f3 * bf2f(u3.w);
  }
  for (; j < len; ++j) {
    const int s0 = bk[j];
    const float f0 = dinv[s0];
    ushort4 u0 = ((const ushort4*)(hb + (size_t)s0 * D))[lane];
    a0.x += f0 * bf2f(u0.x); a0.y += f0 * bf2f(u0.y); a0.z += f0 * bf2f(u0.z); a0.w += f0 * bf2f(u0.w);
  }

  const float4 bias = ((const float4*)b)[lane];
  float4 v;
  v.x = bias.x + (a0.x + a1.x) + (a2.x + a3.x);
  v.y = bias.y + (a0.y + a1.y) + (a2.y + a3.y);
  v.z = bias.z + (a0.z + a1.z) + (a2.z + a3.z);
  v.w = bias.w + (a0.w + a1.w) + (a2.w + a3.w);
  ((float4*)(out + (size_t)node * D))[lane] = v;
}

extern "C" void kernel_launch(void* const* d_in, const int* in_sizes, int n_in,
                              void* d_out, int out_size, void* d_ws, size_t ws_size,
                              hipStream_t stream) {
  const float* x = (const float*)d_in[0];
  const float* W = (const float*)d_in[1];
  const float* b = (const float*)d_in[2];
  const int* ei = (const int*)d_in[3];
  const int* src = ei;            // edge_index[0]
  const int* dst = ei + N_EDGES;  // edge_index[1]
  float* out = (float*)d_out;

  char* ws = (char*)d_ws;
  float* dinv = (float*)(ws + 0);                          // 160,000
  unsigned* slabS = (unsigned*)(ws + 160000);              // 2,560,000
  unsigned short* Wb = (unsigned short*)(ws + 2720000);    // 32,768
  unsigned* slabP = (unsigned*)(ws + 2752768);             // 391,876 (+pad)
  unsigned* rowbase = (unsigned*)(ws + 3144960);           // 391,876 (+pad)
  unsigned* keytotal = (unsigned*)(ws + 3537152);          // 1,252 (+pad)
  unsigned* epack = (unsigned*)(ws + 3541248);             // 2,560,000
  int* offs = (int*)(ws + 6101248);                        // 160,000
  int* cnt_dst = (int*)(ws + 6261248);                     // 160,000
  unsigned short* esrc16 = (unsigned short*)(ws + 6421248);// 1,280,000
  unsigned short* hb = (unsigned short*)(ws + 7701248);    // 10,240,000 (17.9 MB)

  k_prep<<<64, 256, 0, stream>>>(W, Wb);
  k1<<<SRCH_BLKS + 939, 256, 0, stream>>>(x, Wb, src, dst, slabS, slabP, hb);
  k2<<<NKEY + 79, 256, 0, stream>>>(slabP, slabS, rowbase, keytotal, dinv);
  k3<<<P1BLKS, 256, 0, stream>>>(src, dst, rowbase, keytotal, epack);
  k4a<<<NKEY, 256, 0, stream>>>(keytotal, epack, offs, cnt_dst, esrc16);
  k4b<<<5000, 256, 0, stream>>>(offs, cnt_dst, dinv, esrc16, hb, b, out);
}

// Round 12
// 66.230 us; speedup vs baseline: 1.4018x; 1.1081x over previous
//
#include <hip/hip_runtime.h>

#define N_NODES 40000
#define D 128
#define N_EDGES 640000
#define GRP 128     // dst nodes per key group
#define NKEY 313    // ceil(N_NODES / GRP)
#define P1TILE 2048 // edges per partition tile
#define P1BLKS 313  // ceil(N_EDGES / P1TILE)
// src-degree histogram (proven rounds 7-11):
#define NSLICE 32
#define SLICE_E 20000
#define SLICE_E4 5000
#define HALF_BINS 20000
#define HALF_W 10000
#define WROW 20000
#define SRCH_BLKS 64
#define GEMM_BLKS 625  // x 64 nodes
#define XP 136         // bf16 x-tile pitch in shorts (272 B rows, 16B-aligned)

typedef __attribute__((ext_vector_type(8))) short short8_t;
typedef __attribute__((ext_vector_type(4))) float float4_t;

static __device__ __forceinline__ unsigned short f2bf(float f) {
  unsigned u = __float_as_uint(f);
  return (unsigned short)((u + 0x7fffu + ((u >> 16) & 1u)) >> 16);  // RNE
}
static __device__ __forceinline__ float bf2f(unsigned short h) {
  return __uint_as_float(((unsigned)h) << 16);
}

// Inclusive Hillis-Steele scan over s[0..511]; 256 threads, 2 indices each.
static __device__ __forceinline__ void scan512(unsigned* s, int tid) {
  const int t2 = tid + 256;
#pragma unroll
  for (int off = 1; off < 512; off <<= 1) {
    unsigned a = (tid >= off) ? s[tid - off] : 0u;
    unsigned c = (t2 >= off) ? s[t2 - off] : 0u;
    __syncthreads();
    s[tid] += a;
    s[t2] += c;
    __syncthreads();
  }
}

// ---------------------------------------------------------------------------
// k1 — three roles (round-11 proven), no global atomics; W repack fused in:
//  bid < 64         : src-hist slab, u16-packed LDS histogram.
//  t=bid-64, t%3==2 : p1-hist: LDS count of dst>>7 keys for tile t/3.
//  else             : MFMA GEMM: each block self-repacks W (fp32->bf16 frags
//                     in LDS) and stages x as bf16; hb = bf16(x@W) unscaled.
// ---------------------------------------------------------------------------
__global__ __launch_bounds__(256) void k1(
    const float* __restrict__ x, const float* __restrict__ W,
    const int* __restrict__ src, const int* __restrict__ dst,
    unsigned* __restrict__ slabS, unsigned* __restrict__ slabP,
    unsigned short* __restrict__ hb) {
  __shared__ unsigned smem[12544];  // 50176 B union
  const int bid = blockIdx.x;
  const int tid = threadIdx.x;

  if (bid < SRCH_BLKS) {
    const int b = bid >> 1;
    const int h = bid & 1;
    for (int i = tid; i < HALF_W; i += 256) smem[i] = 0;
    __syncthreads();
    const int4* p4 = (const int4*)(src + b * SLICE_E);
    const unsigned lo = (unsigned)(h * HALF_BINS);
    for (int it = tid; it < SLICE_E4; it += 256) {
      const int4 v = p4[it];
      unsigned u;
      u = (unsigned)v.x - lo; if (u < HALF_BINS) atomicAdd(&smem[u >> 1], 1u << ((u & 1) * 16));
      u = (unsigned)v.y - lo; if (u < HALF_BINS) atomicAdd(&smem[u >> 1], 1u << ((u & 1) * 16));
      u = (unsigned)v.z - lo; if (u < HALF_BINS) atomicAdd(&smem[u >> 1], 1u << ((u & 1) * 16));
      u = (unsigned)v.w - lo; if (u < HALF_BINS) atomicAdd(&smem[u >> 1], 1u << ((u & 1) * 16));
    }
    __syncthreads();
    unsigned* row = slabS + (size_t)b * WROW + h * HALF_W;
    for (int i = tid; i < HALF_W; i += 256) row[i] = smem[i];
    return;
  }

  const int t = bid - SRCH_BLKS;
  if (t % 3 == 2) {
    const int cid = t / 3;    // 0..312
    unsigned* cnt = smem;     // [NKEY]
    const int t2 = tid + 256;
    if (tid < NKEY) cnt[tid] = 0;
    if (t2 < NKEY) cnt[t2] = 0;
    __syncthreads();
    const int e0 = cid * P1TILE + tid * 8;
    if (e0 < N_EDGES) {
      const int4 da = *(const int4*)(dst + e0);
      const int4 db = *(const int4*)(dst + e0 + 4);
      atomicAdd(&cnt[da.x >> 7], 1u);
      atomicAdd(&cnt[da.y >> 7], 1u);
      atomicAdd(&cnt[da.z >> 7], 1u);
      atomicAdd(&cnt[da.w >> 7], 1u);
      atomicAdd(&cnt[db.x >> 7], 1u);
      atomicAdd(&cnt[db.y >> 7], 1u);
      atomicAdd(&cnt[db.z >> 7], 1u);
      atomicAdd(&cnt[db.w >> 7], 1u);
    }
    __syncthreads();
    if (tid < NKEY) slabP[(size_t)cid * NKEY + tid] = cnt[tid];
    if (t2 < NKEY) slabP[(size_t)cid * NKEY + t2] = cnt[t2];
    return;
  }

  // ---------------- MFMA GEMM role (W self-repack) ----------------
  const int gid = 2 * (t / 3) + (t % 3);
  if (gid >= GEMM_BLKS) return;
  const int n0 = gid * 64;
  const int w = tid >> 6;
  const int lane = tid & 63;

  unsigned short* wb = (unsigned short*)smem;  // 16384 shorts = 32 KB
  unsigned short* xb = wb + 16384;             // 64 x XP shorts = 17 KB

  // repack W: coalesced float4 reads, scattered bf16 LDS writes
#pragma unroll 4
  for (int i = 0; i < 16; ++i) {
    const int g4 = i * 256 + tid;  // 0..4095 float4s of W
    const int k = g4 >> 5;
    const int d0 = (g4 & 31) * 4;
    const float4 v = ((const float4*)W)[g4];
    const int q = k >> 5, r = k & 31;
    const int base =
        (((d0 >> 4) * 4 + q) * 64 + ((r >> 3) * 16 + (d0 & 15))) * 8 + (r & 7);
    wb[base] = f2bf(v.x);
    wb[base + 8] = f2bf(v.y);
    wb[base + 16] = f2bf(v.z);
    wb[base + 24] = f2bf(v.w);
  }

  // stage x tile as bf16
  {
    const float4* xg = (const float4*)(x + (size_t)n0 * D);
#pragma unroll
    for (int j = 0; j < 8; ++j) {
      const int idx = tid + j * 256;  // 0..2047
      const int row = idx >> 5;
      const int c4 = idx & 31;
      const float4 v = xg[idx];
      ushort4 o;
      o.x = f2bf(v.x); o.y = f2bf(v.y); o.z = f2bf(v.z); o.w = f2bf(v.w);
      *(ushort4*)(xb + row * XP + c4 * 4) = o;
    }
  }
  __syncthreads();

  short8_t afrag[4];
  {
    const unsigned short* ap0 = xb + (w * 16 + (lane & 15)) * XP + (lane >> 4) * 8;
#pragma unroll
    for (int q = 0; q < 4; ++q) afrag[q] = *(const short8_t*)(ap0 + q * 32);
  }

  const int orow = n0 + w * 16 + (lane >> 4) * 4;
  const int ocolbase = lane & 15;
#pragma unroll
  for (int t8 = 0; t8 < 8; ++t8) {
    float4_t acc = {0.f, 0.f, 0.f, 0.f};
#pragma unroll
    for (int q = 0; q < 4; ++q) {
      const short8_t bfrag = *(const short8_t*)(wb + ((t8 * 4 + q) * 64 + lane) * 8);
      acc = __builtin_amdgcn_mfma_f32_16x16x32_bf16(afrag[q], bfrag, acc, 0, 0, 0);
    }
    const int col = t8 * 16 + ocolbase;
#pragma unroll
    for (int r = 0; r < 4; ++r)
      hb[(size_t)(orow + r) * D + col] = f2bf(acc[r]);
  }
}

// ---------------------------------------------------------------------------
// k2 — bid < NKEY: per-key exclusive prefix over tiles -> rowbase + keytotal.
//      bid >= NKEY: dinv colsum from src slab. (round-10/11 proven)
// ---------------------------------------------------------------------------
__global__ __launch_bounds__(256) void k2(
    const unsigned* __restrict__ slabP, const unsigned* __restrict__ slabS,
    unsigned* __restrict__ rowbase, unsigned* __restrict__ keytotal,
    float* __restrict__ dinv) {
  const int bid = blockIdx.x;
  const int tid = threadIdx.x;
  if (bid < NKEY) {
    const int k = bid;
    __shared__ unsigned s[512];
    const int t2 = tid + 256;
    unsigned v0 = slabP[(size_t)tid * NKEY + k];
    unsigned v1 = (t2 < NKEY) ? slabP[(size_t)t2 * NKEY + k] : 0u;
    s[tid] = v0;
    s[t2] = v1;
    __syncthreads();
    scan512(s, tid);
    rowbase[(size_t)tid * NKEY + k] = s[tid] - v0;
    if (t2 < NKEY) rowbase[(size_t)t2 * NKEY + k] = s[t2] - v1;
    if (tid == 0) keytotal[k] = s[NKEY - 1];
    return;
  }
  const int w = (bid - NKEY) * 256 + tid;
  if (w >= WROW) return;
  unsigned run = 0;
#pragma unroll 8
  for (int b = 0; b < NSLICE; ++b) run += slabS[(size_t)b * WROW + w];
  const unsigned lo = run & 0xFFFFu;
  const unsigned hi = run >> 16;
  dinv[2 * w] = lo ? 1.0f / (float)lo : 0.0f;
  dinv[2 * w + 1] = hi ? 1.0f / (float)hi : 0.0f;
}

// ---------------------------------------------------------------------------
// k3 — partition scatter (round-10/11 proven): edge -> epack[ko[key] +
//      rowbase[tile][key] + LDS-rank], pack = (dst&127)<<16 | src.
// ---------------------------------------------------------------------------
__global__ __launch_bounds__(256) void k3(
    const int* __restrict__ src, const int* __restrict__ dst,
    const unsigned* __restrict__ rowbase, const unsigned* __restrict__ keytotal,
    unsigned* __restrict__ epack) {
  __shared__ unsigned s[512];
  __shared__ unsigned ko[NKEY];
  __shared__ unsigned rb[NKEY];
  __shared__ unsigned cnt[NKEY];
  const int b = blockIdx.x;
  const int tid = threadIdx.x;
  const int t2 = tid + 256;

  unsigned kv0 = (tid < NKEY) ? keytotal[tid] : 0u;
  unsigned kv1 = (t2 < NKEY) ? keytotal[t2] : 0u;
  s[tid] = kv0;
  s[t2] = kv1;
  if (tid < NKEY) { rb[tid] = rowbase[(size_t)b * NKEY + tid]; cnt[tid] = 0; }
  if (t2 < NKEY) { rb[t2] = rowbase[(size_t)b * NKEY + t2]; cnt[t2] = 0; }
  __syncthreads();
  scan512(s, tid);
  if (tid < NKEY) ko[tid] = s[tid] - kv0;
  if (t2 < NKEY) ko[t2] = s[t2] - kv1;
  __syncthreads();

  const int e0 = b * P1TILE + tid * 8;
  if (e0 < N_EDGES) {
    const int4 sa = *(const int4*)(src + e0);
    const int4 sb = *(const int4*)(src + e0 + 4);
    const int4 da = *(const int4*)(dst + e0);
    const int4 db = *(const int4*)(dst + e0 + 4);
#define PLACE(DV, SV)                                                   \
  {                                                                     \
    const int d_ = (DV);                                                \
    const int k_ = d_ >> 7;                                             \
    const unsigned lr_ = atomicAdd(&cnt[k_], 1u);                       \
    epack[ko[k_] + rb[k_] + lr_] =                                      \
        ((unsigned)(d_ & 127) << 16) | (unsigned)(SV);                  \
  }
    PLACE(da.x, sa.x) PLACE(da.y, sa.y) PLACE(da.z, sa.z) PLACE(da.w, sa.w)
    PLACE(db.x, sb.x) PLACE(db.y, sb.y) PLACE(db.z, sb.z) PLACE(db.w, sb.w)
#undef PLACE
  }
}

// ---------------------------------------------------------------------------
// k4a — per key group: dense CSR materialization (round-11 proven).
// ---------------------------------------------------------------------------
__global__ __launch_bounds__(256) void k4a(
    const unsigned* __restrict__ keytotal, const unsigned* __restrict__ epack,
    int* __restrict__ offs, int* __restrict__ cnt_dst,
    unsigned short* __restrict__ esrc16) {
  __shared__ unsigned s[512];
  __shared__ unsigned cnt[GRP];
  __shared__ unsigned cur[GRP];
  __shared__ unsigned sstart, slen;
  const int k = blockIdx.x;
  const int tid = threadIdx.x;
  const int t2 = tid + 256;

  unsigned kv0 = (tid < NKEY) ? keytotal[tid] : 0u;
  unsigned kv1 = (t2 < NKEY) ? keytotal[t2] : 0u;
  s[tid] = kv0;
  s[t2] = kv1;
  if (tid < GRP) cnt[tid] = 0;
  __syncthreads();
  scan512(s, tid);
  if (tid == 0) {
    sstart = s[k] - keytotal[k];
    slen = keytotal[k];
  }
  __syncthreads();
  const unsigned start = sstart;
  const unsigned len = slen;

  for (unsigned i = tid; i < len; i += 256) {
    atomicAdd(&cnt[epack[start + i] >> 16], 1u);
  }
  __syncthreads();

  unsigned v = (tid < GRP) ? cnt[tid] : 0u;
  s[tid] = v;
  __syncthreads();
#pragma unroll
  for (int off = 1; off < 256; off <<= 1) {
    unsigned a = (tid >= off) ? s[tid - off] : 0u;
    __syncthreads();
    s[tid] += a;
    __syncthreads();
  }
  if (tid < GRP) {
    const unsigned ex = s[tid] - v;
    cur[tid] = ex;
    const int n = k * GRP + tid;
    if (n < N_NODES) {
      offs[n] = (int)(start + ex);
      cnt_dst[n] = (int)v;
    }
  }
  __syncthreads();

  for (unsigned i = tid; i < len; i += 256) {
    const unsigned p = epack[start + i];
    const unsigned dl = p >> 16;
    const unsigned r = atomicAdd(&cur[dl], 1u);
    esrc16[start + r] = (unsigned short)(p & 0xFFFFu);
  }
}

// ---------------------------------------------------------------------------
// k4b — shuffle-batched gather: lane j of each 32-lane node-group caches
// edge j's (src, dinv); hb row loads issued in batches of 8 via shfl-
// broadcast (no load->load dependence), 4 rotating accumulators.
// ---------------------------------------------------------------------------
__global__ __launch_bounds__(256) void k4b(
    const int* __restrict__ offs, const int* __restrict__ cnt_dst,
    const float* __restrict__ dinv, const unsigned short* __restrict__ esrc16,
    const unsigned short* __restrict__ hb,
    const float* __restrict__ b, float* __restrict__ out) {
  const int tid = threadIdx.x;
  const int node = blockIdx.x * 8 + (tid >> 5);
  const int lane = tid & 31;

  const int start = offs[node];
  const int len = cnt_dst[node];
  const unsigned short* bk = esrc16 + start;

  // lane j holds edge j's src + weight (one coalesced u16 load per group,
  // 32 parallel dinv loads)
  int sj = 0;
  if (lane < len) sj = bk[lane];
  const float fj = dinv[sj];

  float4 aa[4];
#pragma unroll
  for (int q = 0; q < 4; ++q) aa[q] = make_float4(0.f, 0.f, 0.f, 0.f);

  const int l32 = len < 32 ? len : 32;
  for (int jj = 0; jj < l32; jj += 8) {
    ushort4 u[8];
    float fq[8];
#pragma unroll
    for (int q = 0; q < 8; ++q) {
      const int j = jj + q;
      const int s = __shfl(sj, j, 32);
      const float f = __shfl(fj, j, 32);
      const bool on = j < l32;
      const int ss = on ? s : 0;
      u[q] = ((const ushort4*)(hb + (size_t)ss * D))[lane];  // row 0 if off
      fq[q] = on ? f : 0.0f;
    }
#pragma unroll
    for (int q = 0; q < 8; ++q) {
      const float f = fq[q];
      float4& a = aa[q & 3];
      a.x += f * bf2f(u[q].x);
      a.y += f * bf2f(u[q].y);
      a.z += f * bf2f(u[q].z);
      a.w += f * bf2f(u[q].w);
    }
  }
  // rare tail: in-degree > 32
  for (int j = 32; j < len; ++j) {
    const int s = bk[j];
    const float f = dinv[s];
    ushort4 u = ((const ushort4*)(hb + (size_t)s * D))[lane];
    aa[0].x += f * bf2f(u.x);
    aa[0].y += f * bf2f(u.y);
    aa[0].z += f * bf2f(u.z);
    aa[0].w += f * bf2f(u.w);
  }

  const float4 bias = ((const float4*)b)[lane];
  float4 v;
  v.x = bias.x + (aa[0].x + aa[1].x) + (aa[2].x + aa[3].x);
  v.y = bias.y + (aa[0].y + aa[1].y) + (aa[2].y + aa[3].y);
  v.z = bias.z + (aa[0].z + aa[1].z) + (aa[2].z + aa[3].z);
  v.w = bias.w + (aa[0].w + aa[1].w) + (aa[2].w + aa[3].w);
  ((float4*)(out + (size_t)node * D))[lane] = v;
}

extern "C" void kernel_launch(void* const* d_in, const int* in_sizes, int n_in,
                              void* d_out, int out_size, void* d_ws, size_t ws_size,
                              hipStream_t stream) {
  const float* x = (const float*)d_in[0];
  const float* W = (const float*)d_in[1];
  const float* b = (const float*)d_in[2];
  const int* ei = (const int*)d_in[3];
  const int* src = ei;            // edge_index[0]
  const int* dst = ei + N_EDGES;  // edge_index[1]
  float* out = (float*)d_out;

  char* ws = (char*)d_ws;
  float* dinv = (float*)(ws + 0);                          // 160,000
  unsigned* slabS = (unsigned*)(ws + 160000);              // 2,560,000
  unsigned* slabP = (unsigned*)(ws + 2720000);             // 391,876 (+pad)
  unsigned* rowbase = (unsigned*)(ws + 3112192);           // 391,876 (+pad)
  unsigned* keytotal = (unsigned*)(ws + 3504384);          // 1,252 (+pad)
  unsigned* epack = (unsigned*)(ws + 3508480);             // 2,560,000
  int* offs = (int*)(ws + 6068480);                        // 160,000
  int* cnt_dst = (int*)(ws + 6228480);                     // 160,000
  unsigned short* esrc16 = (unsigned short*)(ws + 6388480);// 1,280,000
  unsigned short* hb = (unsigned short*)(ws + 7668480);    // 10,240,000 (17.9 MB)

  k1<<<SRCH_BLKS + 939, 256, 0, stream>>>(x, W, src, dst, slabS, slabP, hb);
  k2<<<NKEY + 79, 256, 0, stream>>>(slabP, slabS, rowbase, keytotal, dinv);
  k3<<<P1BLKS, 256, 0, stream>>>(src, dst, rowbase, keytotal, epack);
  k4a<<<NKEY, 256, 0, stream>>>(keytotal, epack, offs, cnt_dst, esrc16);
  k4b<<<5000, 256, 0, stream>>>(offs, cnt_dst, dinv, esrc16, hb, b, out);
}